// Round 1
// baseline (543.180 us; speedup 1.0000x reference)
//
#include <hip/hip_runtime.h>

// ST_Affine: affine_grid (align_corners=False) + grid_sample bilinear/zeros.
// B=16, C=64, H=W=256, fp32 in/out.
// One thread per (b,h,w); coords computed once, 64-channel inner loop.
// Lanes vary over w -> coalesced stores per channel iter; b uniform per block
// -> theta loads are scalar.

constexpr int B = 16, C = 64, H = 256, W = 256;
constexpr int HW = H * W;        // 65536
constexpr int CHW = C * HW;      // 4194304

__global__ __launch_bounds__(256) void st_affine_kernel(
    const float* __restrict__ x, const float* __restrict__ theta,
    float* __restrict__ out)
{
    const int tid = blockIdx.x * 256 + threadIdx.x;   // 0 .. B*HW-1
    const int b  = tid >> 16;          // HW = 2^16
    const int hw = tid & (HW - 1);
    const int h  = hw >> 8;            // W = 2^8
    const int w  = hw & (W - 1);

    // theta[b, 2, 3] row-major flat: [t00 t01 t02 t10 t11 t12]
    const float* th = theta + b * 6;
    const float t0 = th[0], t1 = th[1], t2 = th[2];
    const float t3 = th[3], t4 = th[4], t5 = th[5];

    // normalized pixel centers, align_corners=False
    const float gx = (w + 0.5f) * (2.0f / W) - 1.0f;
    const float gy = (h + 0.5f) * (2.0f / H) - 1.0f;

    const float sx = t0 * gx + t1 * gy + t2;   // grid[...,0]
    const float sy = t3 * gx + t4 * gy + t5;   // grid[...,1]

    // unnormalize to source pixel units
    const float ix = ((sx + 1.0f) * (float)W - 1.0f) * 0.5f;
    const float iy = ((sy + 1.0f) * (float)H - 1.0f) * 0.5f;

    const float ix0f = floorf(ix);
    const float iy0f = floorf(iy);
    const float tx = ix - ix0f;
    const float ty = iy - iy0f;
    const int ix0 = (int)ix0f, iy0 = (int)iy0f;
    const int ix1 = ix0 + 1,   iy1 = iy0 + 1;

    // bilinear weights, zeroed where the (unclamped) corner is out of bounds
    const float vx0 = (ix0 >= 0 && ix0 < W) ? 1.0f : 0.0f;
    const float vx1 = (ix1 >= 0 && ix1 < W) ? 1.0f : 0.0f;
    const float vy0 = (iy0 >= 0 && iy0 < H) ? 1.0f : 0.0f;
    const float vy1 = (iy1 >= 0 && iy1 < H) ? 1.0f : 0.0f;

    const float w00 = (1.0f - tx) * (1.0f - ty) * vx0 * vy0;
    const float w01 = tx          * (1.0f - ty) * vx1 * vy0;
    const float w10 = (1.0f - tx) * ty          * vx0 * vy1;
    const float w11 = tx          * ty          * vx1 * vy1;

    // clamped offsets (always-safe loads; invalid corners have weight 0)
    const int cx0 = min(max(ix0, 0), W - 1);
    const int cx1 = min(max(ix1, 0), W - 1);
    const int cy0 = min(max(iy0, 0), H - 1);
    const int cy1 = min(max(iy1, 0), H - 1);

    const int off00 = cy0 * W + cx0;
    const int off01 = cy0 * W + cx1;
    const int off10 = cy1 * W + cx0;
    const int off11 = cy1 * W + cx1;

    const float* __restrict__ xb = x + (size_t)b * CHW;
    float* __restrict__ ob = out + (size_t)b * CHW + hw;

#pragma unroll 4
    for (int c = 0; c < C; ++c) {
        const float* __restrict__ xc = xb + c * HW;
        const float v = xc[off00] * w00 + xc[off01] * w01
                      + xc[off10] * w10 + xc[off11] * w11;
        ob[c * HW] = v;
    }
}

extern "C" void kernel_launch(void* const* d_in, const int* in_sizes, int n_in,
                              void* d_out, int out_size, void* d_ws, size_t ws_size,
                              hipStream_t stream) {
    const float* x     = (const float*)d_in[0];
    const float* theta = (const float*)d_in[1];
    float* out = (float*)d_out;

    const int total = B * HW;              // one thread per (b,h,w)
    dim3 grid(total / 256), block(256);
    st_affine_kernel<<<grid, block, 0, stream>>>(x, theta, out);
}